// Round 5
// baseline (901.817 us; speedup 1.0000x reference)
//
#include <hip/hip_runtime.h>
#include <cstdint>
#include <cstddef>

// LinearAttention MI355X round 8: k_gemm occupancy fix — BK=32, 72KB LDS
// ring -> 2 blocks/CU (was 147KB -> 1 block/CU, zero inter-block overlap).
//   y = attout · Wout^T  with  attout = q' · ctx   collapses to
//   y[p][o] = sum_C Q'[p][C] · Mt[b][o][C],  C = h*96+d,
//   Mt[b][o][h*96+d] = (1/Z[bh][d]) · sum_e ctx[bh][d][e] · Wout[o][h*96+e].
//
// Layouts (P = 65536 global pixels = b*4096+pix, b in 0..15):
//   xn     bf16 [P][384]
//   qkv    bf16: q [4][P][96] ; ekT [4][96][P] (holds exp(k)) ; vT [4][96][P]
//   Qp     bf16 [P][384]  (softmaxed q, head-interleaved)
//   y      bf16 [P][384]  (at qkv base; q/ekT/vT dead by then)
//   ctxs   fp32 [8][64][96][96] + zs fp32 [8][64][96]   -> scratch in d_out
//   Mt     bf16 [16][384][384]                           -> scratch in d_out
//   ctxred fp32 [64][96][96], zred fp32 [64][96]        -> ws
//   wbf    bf16 Wqkv(1152x384) then Wout(384x384)
//
// ws offsets (bytes): xn @0 (50,331,648) | qkv @50,331,648 (150,994,944)
//   Qp @201,326,592 (50,331,648) | ctxred @251,658,240 (2,359,296)
//   zred @254,017,536 (24,576) | wbf @254,042,112 (1,179,648)
// d_out scratch: ctxs @0 (18,874,368) | zs @18,874,368 (196,608)
//   Mt @19,070,976 (4,718,592; ends 23,789,568) -- dead before k_outnorm.

#define P_     65536
#define P96_   6291456
#define ROW_   384
#define NS_    8            // ctx pixel splits per (b,h)
#define CHK_   512          // 4096 / NS_
#define SCALE_ 0.10206207261596577f
#define EPS_   1e-5f

typedef unsigned short us16;
typedef __attribute__((ext_vector_type(8))) unsigned short ushort8;
typedef __attribute__((ext_vector_type(8))) short short8;
typedef __attribute__((ext_vector_type(4))) float f32x4;
typedef __attribute__((ext_vector_type(2))) unsigned int uint2v;

static __device__ __forceinline__ float bfu2f(us16 u) {
  union { float f; unsigned int i; } x; x.i = ((unsigned int)u) << 16; return x.f;
}
static __device__ __forceinline__ us16 f2bfu(float f) {
  union { float f; unsigned int u; } x; x.f = f;
  unsigned int r = x.u + 0x7fffu + ((x.u >> 16) & 1u);
  return (us16)(r >> 16);
}

#define GLDS16(gp, lp) \
  __builtin_amdgcn_global_load_lds((const __attribute__((address_space(1))) void*)(gp), \
                                   (__attribute__((address_space(3))) void*)(lp), 16, 0, 0)

// ---------------- W fp32 -> bf16 ----------------
__global__ __launch_bounds__(256) void k_wcvt(const float* __restrict__ wqkv,
                                              const float* __restrict__ wout,
                                              us16* __restrict__ wbf) {
  int i = (blockIdx.x * 256 + threadIdx.x) * 4;
  const float* s = (i < 442368) ? (wqkv + i) : (wout + (i - 442368));
  wbf[i + 0] = f2bfu(s[0]); wbf[i + 1] = f2bfu(s[1]);
  wbf[i + 2] = f2bfu(s[2]); wbf[i + 3] = f2bfu(s[3]);
}

// ---------------- K1: prenorm ----------------
__global__ __launch_bounds__(256) void k_prenorm(const float* __restrict__ x,
                                                 const float* __restrict__ g,
                                                 us16* __restrict__ xn) {
  __shared__ float gs[384];
  __shared__ float sm[4][64], sq[4][64];
  int t = threadIdx.x;
  for (int c = t; c < 384; c += 256) gs[c] = g[c];
  int qd = t >> 6, pb = t & 63;
  int p = blockIdx.x * 64 + pb;
  int b = p >> 12, pix = p & 4095;
  const float* xb = x + (size_t)b * 1572864 + pix;
  float xv[96];
  float s1 = 0.f, s2 = 0.f;
  #pragma unroll
  for (int i = 0; i < 96; ++i) {
    float v = xb[(size_t)(qd * 96 + i) * 4096];
    xv[i] = v; s1 += v; s2 += v * v;
  }
  sm[qd][pb] = s1; sq[qd][pb] = s2;
  __syncthreads();
  float su = sm[0][pb] + sm[1][pb] + sm[2][pb] + sm[3][pb];
  float ss = sq[0][pb] + sq[1][pb] + sq[2][pb] + sq[3][pb];
  float mean = su * (1.f / 384);
  float var = ss * (1.f / 384) - mean * mean;
  float rs = rsqrtf(var + EPS_);
  us16* ob = xn + (size_t)p * ROW_ + qd * 96;
  #pragma unroll
  for (int c8 = 0; c8 < 12; ++c8) {
    ushort8 u;
    #pragma unroll
    for (int j = 0; j < 8; ++j)
      u[j] = f2bfu((xv[c8 * 8 + j] - mean) * rs * gs[qd * 96 + c8 * 8 + j]);
    *(ushort8*)(ob + c8 * 8) = u;
  }
}

// ---------------- MFMA GEMM: dst[p][o] = sum_c src[p][c] * W[o][c] --------
// BM=256 BN=128 BK=32, 8 waves (4Mx2N), 3-deep LDS ring (72KB -> 2 blk/CU),
// counted vmcnt(3) (T3+T4), XOR-swizzled staging (T2: g ^= (row>>1)&3 for
// 64B rows), setprio (T5), coalesced LDS epilogue.
// mode 0 (QKV): src=xn, W=Wqkv(1152 rows); q/ekT(exp)/vT sections.
// mode 1 (out): src=Qp, W=Mt (PER-BATCH: W + (p0>>12)*147456); dst y [P][384].
__global__ __launch_bounds__(512, 4) void k_gemm(const us16* __restrict__ src,
                                                 const us16* __restrict__ W,
                                                 us16* __restrict__ dst,
                                                 int MT, int mode) {
  // union buffer: ring of 3 slots {A 256x32 (16KB) + B 128x32 (8KB)} = 72KB;
  // epilogue Cs (max 67.6KB) reuses it.
  __shared__ __align__(16) us16 LDS[36864];
  int i = blockIdx.x;
  int xcd = i & 7, idx = i >> 3;
  int ot = idx % MT;
  int pt = (idx / MT) * 8 + xcd;
  int p0 = pt * 256, o0 = ot * 128;
  int tid = threadIdx.x;
  int wv = tid >> 6, l = tid & 63;
  int wr = wv >> 1, wc = wv & 1;       // 4M x 2N wave grid, 64x64 out per wave
  int lm = l & 15, kq = l >> 4;

  bool rm = (mode != 0) || (ot < 3);   // row-major output section?
  bool isk = (mode == 0) && (ot >= 3) && (ot < 6);
  const us16* Wb = (mode != 0) ? (W + (size_t)(p0 >> 12) * 147456) : W;

  // Staging: rows are 64B = 4 x 16B groups; 4 lanes/row, 16 rows/instruction.
  // Swizzle g ^= (row>>1)&3 applied on the GLOBAL source (LDS dest linear).
  int srow = l >> 2;                       // row within 16-row group
  int swz = ((l & 3) ^ ((l >> 3) & 3)) * 8;
  const us16* aB0 = src + (size_t)(p0 + wv * 32 + srow) * ROW_ + swz;
  const us16* aB1 = src + (size_t)(p0 + wv * 32 + 16 + srow) * ROW_ + swz;
  const us16* bB  = Wb  + (size_t)(o0 + wv * 16 + srow) * ROW_ + swz;

  // Fragment ds_read offsets (short8 units): row*4 + (kq ^ ((row>>1)&3)),
  // (row>>1)&3 == (lm>>1)&3 since row-base is a multiple of 16.
  int fswz = (lm >> 1) & 3;
  int aidx[4], bidx[4];
  #pragma unroll
  for (int ii = 0; ii < 4; ++ii)
    aidx[ii] = (wr * 64 + ii * 16 + lm) * 4 + (kq ^ fswz);
  #pragma unroll
  for (int jj = 0; jj < 4; ++jj)
    bidx[jj] = (wc * 64 + jj * 16 + lm) * 4 + (kq ^ fswz);

  f32x4 acc[4][4];
  #pragma unroll
  for (int a = 0; a < 4; ++a)
    #pragma unroll
    for (int q = 0; q < 4; ++q) acc[a][q] = (f32x4)0.f;

  // slot s base (us16): s*12288; B at +8192.
#define STG(t_, s_) do { \
    GLDS16(aB0 + (t_) * 32, &LDS[(s_) * 12288 + (wv * 32) * 32]); \
    GLDS16(aB1 + (t_) * 32, &LDS[(s_) * 12288 + (wv * 32 + 16) * 32]); \
    GLDS16(bB  + (t_) * 32, &LDS[(s_) * 12288 + 8192 + (wv * 16) * 32]); \
  } while (0)

  // Prologue: stage tiles 0 and 1 (6 loads in flight); wait for tile 0 only.
  STG(0, 0);
  STG(1, 1);
  asm volatile("s_waitcnt vmcnt(3)\n\ts_barrier" ::: "memory");

  #pragma unroll
  for (int t = 0; t < 12; ++t) {
    if (t + 2 < 12) STG(t + 2, (t + 2) % 3);
    const short8* A8 = (const short8*)(LDS + (t % 3) * 12288);
    const short8* B8 = (const short8*)(LDS + (t % 3) * 12288 + 8192);
    __builtin_amdgcn_s_setprio(1);
    {
      short8 af[4], bf[4];
      #pragma unroll
      for (int ii = 0; ii < 4; ++ii) af[ii] = A8[aidx[ii]];
      #pragma unroll
      for (int jj = 0; jj < 4; ++jj) bf[jj] = B8[bidx[jj]];
      if (rm) {
        // C^T fragment: D[row=o][col=p]
        #pragma unroll
        for (int ii = 0; ii < 4; ++ii)
          #pragma unroll
          for (int jj = 0; jj < 4; ++jj)
            acc[ii][jj] = __builtin_amdgcn_mfma_f32_16x16x32_bf16(bf[jj], af[ii], acc[ii][jj], 0, 0, 0);
      } else {
        // C fragment: D[row=p][col=o]
        #pragma unroll
        for (int ii = 0; ii < 4; ++ii)
          #pragma unroll
          for (int jj = 0; jj < 4; ++jj)
            acc[ii][jj] = __builtin_amdgcn_mfma_f32_16x16x32_bf16(af[ii], bf[jj], acc[ii][jj], 0, 0, 0);
      }
    }
    __builtin_amdgcn_s_setprio(0);
    // Boundary: counted vmcnt -- loads for t+2 stay in flight across the
    // barrier; lgkmcnt(0) so ds_reads are serviced before slot reuse.
    if (t < 11) {
      if (t + 2 < 12)
        asm volatile("s_waitcnt vmcnt(3) lgkmcnt(0)\n\ts_barrier" ::: "memory");
      else
        asm volatile("s_waitcnt vmcnt(0) lgkmcnt(0)\n\ts_barrier" ::: "memory");
    }
  }
#undef STG

  // ---- epilogue: stage C through LDS, emit coalesced 16B global stores ----
  __syncthreads();
  us16* Cs = LDS;
  const int MS = rm ? 136 : 264;
  #pragma unroll
  for (int ii = 0; ii < 4; ++ii) {
    #pragma unroll
    for (int jj = 0; jj < 4; ++jj) {
      f32x4 v = acc[ii][jj];
      if (isk) {
        #pragma unroll
        for (int r = 0; r < 4; ++r) v[r] = __expf(v[r]);
      }
      alignas(8) us16 b4[4];
      #pragma unroll
      for (int r = 0; r < 4; ++r) b4[r] = f2bfu(v[r]);
      int maj = rm ? (wr * 64 + ii * 16 + lm) : (wc * 64 + jj * 16 + lm);
      int mnr = rm ? (wc * 64 + jj * 16 + kq * 4) : (wr * 64 + ii * 16 + kq * 4);
      *(uint2v*)&Cs[maj * MS + mnr] = *(const uint2v*)b4;
    }
  }
  __syncthreads();

  if (!rm) {
    // ekT/vT: dst[sec*P96 + d*P_ + p], contiguous along p. Coalesced 512B runs.
    #pragma unroll
    for (int it = 0; it < 8; ++it) {
      int c = it * 512 + tid;
      int o_l = c >> 5, p8 = c & 31;
      int o = o0 + o_l, sec = o / 96, d = o - sec * 96;
      ushort8 u = *(const ushort8*)&Cs[o_l * 264 + p8 * 8];
      *(ushort8*)(dst + (size_t)sec * P96_ + (size_t)d * P_ + p0 + p8 * 8) = u;
    }
  } else if (mode) {
    // y[P][384]: 16 threads cover one 256B row chunk-run.
    #pragma unroll
    for (int it = 0; it < 8; ++it) {
      int c = it * 512 + tid;
      int p_l = c >> 4, ch = c & 15;
      ushort8 u = *(const ushort8*)&Cs[p_l * 136 + ch * 8];
      *(ushort8*)(dst + (size_t)(p0 + p_l) * ROW_ + o0 + ch * 8) = u;
    }
  } else {
    // q sections [P][96]: runs of 192B per p-row (16B-aligned chunks).
    #pragma unroll
    for (int it = 0; it < 8; ++it) {
      int c = it * 512 + tid;
      int p_l = c >> 4, ch = c & 15;
      int o = o0 + ch * 8, sec = o / 96, d = o - sec * 96;
      ushort8 u = *(const ushort8*)&Cs[p_l * 136 + ch * 8];
      *(ushort8*)(dst + (size_t)sec * P96_ + (size_t)(p0 + p_l) * 96 + d) = u;
    }
  }
}

// ---------------- K4: MFMA ctx. ctxs[s][bh][d][e] = sum_p ek[d,p] v[e,p] --
__global__ __launch_bounds__(256) void k_ctx(const us16* __restrict__ qkv,
                                             float* __restrict__ ctxs,
                                             float* __restrict__ zs) {
  __shared__ __align__(16) us16 Ek[96 * 64];
  __shared__ __align__(16) us16 Vv[96 * 64];
  int bh = blockIdx.x, s = blockIdx.y;
  int b = bh >> 2, h = bh & 3;
  const us16* kb = qkv + (size_t)(4 + h) * P96_;
  const us16* vb = qkv + (size_t)(8 + h) * P96_;
  int pbase = b * 4096 + s * CHK_;
  int t = threadIdx.x;
  int wv = t >> 6, l = t & 63;
  int wr = wv >> 1, wc = wv & 1;
  int lm = l & 15, kq = l >> 4;

  f32x4 acc[3][3];
  f32x4 accz[3];
  #pragma unroll
  for (int a = 0; a < 3; ++a) {
    accz[a] = (f32x4)0.f;
    #pragma unroll
    for (int q = 0; q < 3; ++q) acc[a][q] = (f32x4)0.f;
  }
  short8 vone;
  #pragma unroll
  for (int j = 0; j < 8; ++j) vone[j] = (short)0x3F80;   // bf16 1.0

  int srow = wv * 24 + (l >> 3);
  int sgrp = l & 7;

  for (int tile = 0; tile < CHK_ / 64; ++tile) {
    int p0 = pbase + tile * 64;
    #pragma unroll
    for (int c = 0; c < 3; ++c) {
      int r = srow + c * 8;
      int g = sgrp ^ (r & 7);
      GLDS16(kb + (size_t)r * P_ + p0 + g * 8, &Ek[(wv * 24 + c * 8) * 64]);
      GLDS16(vb + (size_t)r * P_ + p0 + g * 8, &Vv[(wv * 24 + c * 8) * 64]);
    }
    __syncthreads();
    const short8* A8 = (const short8*)Ek;
    const short8* B8 = (const short8*)Vv;
    #pragma unroll
    for (int ks = 0; ks < 2; ++ks) {
      short8 af[3], bf[3];
      #pragma unroll
      for (int ii = 0; ii < 3; ++ii) {
        int m = wr * 48 + ii * 16 + lm;
        af[ii] = A8[m * 8 + (((ks * 4 + kq) ^ m) & 7) + ((ks * 4 + kq) & 8)];
        int e = wc * 48 + ii * 16 + lm;
        bf[ii] = B8[e * 8 + (((ks * 4 + kq) ^ e) & 7) + ((ks * 4 + kq) & 8)];
      }
      #pragma unroll
      for (int ii = 0; ii < 3; ++ii)
        #pragma unroll
        for (int jj = 0; jj < 3; ++jj)
          acc[ii][jj] = __builtin_amdgcn_mfma_f32_16x16x32_bf16(af[ii], bf[jj], acc[ii][jj], 0, 0, 0);
      if (wc == 0) {
        #pragma unroll
        for (int ii = 0; ii < 3; ++ii)
          accz[ii] = __builtin_amdgcn_mfma_f32_16x16x32_bf16(af[ii], vone, accz[ii], 0, 0, 0);
      }
    }
    __syncthreads();
  }

  float* cb = ctxs + (size_t)(s * 64 + bh) * 9216;
  #pragma unroll
  for (int ii = 0; ii < 3; ++ii) {
    int m0 = wr * 48 + ii * 16 + kq * 4;
    #pragma unroll
    for (int jj = 0; jj < 3; ++jj) {
      int e = wc * 48 + jj * 16 + lm;
      #pragma unroll
      for (int r = 0; r < 4; ++r)
        cb[(size_t)(m0 + r) * 96 + e] = acc[ii][jj][r];
    }
  }
  if (wc == 0 && lm == 0) {
    #pragma unroll
    for (int ii = 0; ii < 3; ++ii) {
      int m0 = wr * 48 + ii * 16 + kq * 4;
      #pragma unroll
      for (int r = 0; r < 4; ++r)
        zs[(size_t)(s * 64 + bh) * 96 + m0 + r] = accz[ii][r];
    }
  }
}

// ---------------- K4b: reduce the NS_ split slices ------------------------
__global__ __launch_bounds__(256) void k_ctxred(const float* __restrict__ ctxs,
                                                const float* __restrict__ zs,
                                                float* __restrict__ ctx,
                                                float* __restrict__ zr) {
  int bh = blockIdx.x / 9, part = blockIdx.x % 9;
  int t = threadIdx.x;
  int idx = part * 1024 + t * 4;
  f32x4 sum = (f32x4)0.f;
  #pragma unroll
  for (int s = 0; s < NS_; ++s)
    sum += *(const f32x4*)&ctxs[(size_t)(s * 64 + bh) * 9216 + idx];
  *(f32x4*)&ctx[(size_t)bh * 9216 + idx] = sum;
  if (part == 0 && t < 96) {
    float z = 0.f;
    #pragma unroll
    for (int s = 0; s < NS_; ++s) z += zs[(size_t)(s * 64 + bh) * 96 + t];
    zr[bh * 96 + t] = z;
  }
}

// ---------------- K4c: Mt[b][o][h*96+d] = zinv[d] * sum_e ctx[bh][d][e]*Wout[o][h*96+e]
// Tiny MFMA GEMM, hi/lo bf16 split of ctx for ~fp32 accuracy.
// grid 128: blockIdx.x = bh*2 + half (bh 0..63); per block: 192 o x 96 d, K=96.
__global__ __launch_bounds__(256) void k_ctxw(const float* __restrict__ ctx,
                                              const float* __restrict__ zr,
                                              const us16* __restrict__ wout,
                                              us16* __restrict__ Mt) {
  __shared__ __align__(16) us16 Aw[192 * 104];   // Wout slice, padded rows
  __shared__ __align__(16) us16 Bh[96 * 104];    // ctx hi
  __shared__ __align__(16) us16 Bl[96 * 104];    // ctx lo
  int bh = blockIdx.x >> 1, half = blockIdx.x & 1;
  int b = bh >> 2, h = bh & 3;
  int o0 = half * 192;
  int t = threadIdx.x;

  // stage A (Wout rows o0..o0+191, cols h*96..+95): reg-staged, padded LDS
  #pragma unroll
  for (int it = 0; it < 9; ++it) {
    int c = it * 256 + t;             // 16B chunk id, 2304 total
    int row = c / 12, e8 = c % 12;
    ushort8 u = *(const ushort8*)(wout + (size_t)(o0 + row) * 384 + h * 96 + e8 * 8);
    *(ushort8*)&Aw[row * 104 + e8 * 8] = u;
  }
  // stage B: ctx fp32 -> bf16 hi/lo
  const float* cb = ctx + (size_t)bh * 9216;
  #pragma unroll
  for (int it = 0; it < 9; ++it) {
    int c = it * 256 + t;             // f32x4 chunk id, 2304 total
    int fi = c * 4;
    int row = fi / 96, e = fi % 96;
    f32x4 v = *(const f32x4*)&cb[fi];
    alignas(8) us16 hi[4], lo[4];
    #pragma unroll
    for (int r = 0; r < 4; ++r) {
      hi[r] = f2bfu(v[r]);
      lo[r] = f2bfu(v[r] - bfu2f(hi[r]));
    }
    *(uint2v*)&Bh[row * 104 + e] = *(const uint2v*)hi;
    *(uint2v*)&Bl[row * 104 + e] = *(const uint2v*)lo;
  }
  __syncthreads();

  int wv = t >> 6, l = t & 63;
  int lm = l & 15, kq = l >> 4;
  f32x4 acc[3][6];
  #pragma unroll
  for (int a = 0; a < 3; ++a)
    #pragma unroll
    for (int q = 0; q < 6; ++q) acc[a][q] = (f32x4)0.f;

  const short8* A8 = (const short8*)Aw;    // row stride 13 chunks
  const short8* B8h = (const short8*)Bh;
  const short8* B8l = (const short8*)Bl;
  #pragma unroll
  for (int ks = 0; ks < 3; ++ks) {
    short8 af[3];
    #pragma unroll
    for (int ii = 0; ii < 3; ++ii)
      af[ii] = A8[(wv * 48 + ii * 16 + lm) * 13 + ks * 4 + kq];
    #pragma unroll
    for (int jj = 0; jj < 6; ++jj) {
      short8 bh8 = B8h[(jj * 16 + lm) * 13 + ks * 4 + kq];
      short8 bl8 = B8l[(jj * 16 + lm) * 13 + ks * 4 + kq];
      #pragma unroll
      for (int ii = 0; ii < 3; ++ii) {
        acc[ii][jj] = __builtin_amdgcn_mfma_f32_16x16x32_bf16(af[ii], bh8, acc[ii][jj], 0, 0, 0);
        acc[ii][jj] = __builtin_amdgcn_mfma_f32_16x16x32_bf16(af[ii], bl8, acc[ii][jj], 0, 0, 0);
      }
    }
  }

  // D[row=o][col=d]: col = jj*16+lm (d), rows kq*4+r within o 16-block.
  us16* mb = Mt + (size_t)b * 147456;
  #pragma unroll
  for (int jj = 0; jj < 6; ++jj) {
    int d = jj * 16 + lm;
    float zinv = 1.0f / zr[bh * 96 + d];
    #pragma unroll
    for (int ii = 0; ii < 3; ++ii) {
      int orow = o0 + wv * 48 + ii * 16 + kq * 4;
      #pragma unroll
      for (int r = 0; r < 4; ++r)
        mb[(size_t)(orow + r) * 384 + h * 96 + d] = f2bfu(acc[ii][jj][r] * zinv);
    }
  }
}

// ---------------- K5: Q'[p][h*96+d] = softmax_d(q_h[p])*SCALE, bf16 -------
__global__ __launch_bounds__(256) void k_qsm(const us16* __restrict__ qkv,
                                             us16* __restrict__ Qp) {
  int p = blockIdx.x * 256 + threadIdx.x;
  #pragma unroll 1
  for (int h = 0; h < 4; ++h) {
    const us16* qrow = qkv + (size_t)h * P96_ + (size_t)p * 96;
    float qv[96];
    #pragma unroll
    for (int c8 = 0; c8 < 12; ++c8) {
      ushort8 u = *(const ushort8*)(qrow + c8 * 8);
      #pragma unroll
      for (int j = 0; j < 8; ++j) qv[c8 * 8 + j] = bfu2f(u[j]);
    }
    float m = -1e30f;
    #pragma unroll
    for (int d = 0; d < 96; ++d) m = fmaxf(m, qv[d]);
    float s = 0.f;
    #pragma unroll
    for (int d = 0; d < 96; ++d) { qv[d] = __expf(qv[d] - m); s += qv[d]; }
    float sc = SCALE_ / s;
    us16* ob = Qp + (size_t)p * ROW_ + h * 96;
    #pragma unroll
    for (int c8 = 0; c8 < 12; ++c8) {
      ushort8 u;
      #pragma unroll
      for (int j = 0; j < 8; ++j) u[j] = f2bfu(qv[c8 * 8 + j] * sc);
      *(ushort8*)(ob + c8 * 8) = u;
    }
  }
}

// ---------------- K7: +bias, channel LN, *g, +xn, write channel-major fp32
__global__ __launch_bounds__(256) void k_outnorm(const us16* __restrict__ y,
                                                 const us16* __restrict__ xn,
                                                 const float* __restrict__ bout,
                                                 const float* __restrict__ g,
                                                 float* __restrict__ out) {
  __shared__ float bs[384], gs[384];
  int t = threadIdx.x;
  for (int c = t; c < 384; c += 256) { bs[c] = bout[c]; gs[c] = g[c]; }
  __syncthreads();
  int p = blockIdx.x * 256 + t;
  int b = p >> 12, pix = p & 4095;
  const us16* yb = y + (size_t)p * ROW_;
  const us16* xb = xn + (size_t)p * ROW_;
  float sum = 0.f, sq = 0.f;
  #pragma unroll 4
  for (int c8 = 0; c8 < 48; ++c8) {
    ushort8 u = *(const ushort8*)(yb + c8 * 8);
    #pragma unroll
    for (int j = 0; j < 8; ++j) {
      float v = bfu2f(u[j]) + bs[c8 * 8 + j];
      sum += v; sq += v * v;
    }
  }
  float mean = sum * (1.f / 384);
  float var = sq * (1.f / 384) - mean * mean;
  float rs = rsqrtf(var + EPS_);
  float* oB = out + (size_t)b * 1572864 + pix;
  #pragma unroll 2
  for (int c8 = 0; c8 < 48; ++c8) {
    ushort8 u = *(const ushort8*)(yb + c8 * 8);
    ushort8 ux = *(const ushort8*)(xb + c8 * 8);
    #pragma unroll
    for (int j = 0; j < 8; ++j) {
      int c = c8 * 8 + j;
      float v = bfu2f(u[j]) + bs[c];
      oB[(size_t)c * 4096] = (v - mean) * rs * gs[c] + bfu2f(ux[j]);
    }
  }
}

extern "C" void kernel_launch(void* const* d_in, const int* in_sizes, int n_in,
                              void* d_out, int out_size, void* d_ws, size_t ws_size,
                              hipStream_t stream) {
  const float* x    = (const float*)d_in[0];
  const float* pg   = (const float*)d_in[1];
  const float* wqkv = (const float*)d_in[2];
  const float* wout = (const float*)d_in[3];
  const float* bout = (const float*)d_in[4];
  const float* og   = (const float*)d_in[5];

  char* ws = (char*)d_ws;
  us16*  xn     = (us16*)(ws);
  us16*  qkv    = (us16*)(ws + 50331648);
  us16*  Qp     = (us16*)(ws + 201326592);      // softmaxed q
  float* ctxred = (float*)(ws + 251658240);
  float* zred   = (float*)(ws + 254017536);
  us16*  wbf    = (us16*)(ws + 254042112);
  us16*  y      = qkv;                          // q/ekT/vT dead after qsm/gemm1
  float* out    = (float*)d_out;
  // d_out as pre-epilogue scratch (dead until k_outnorm):
  float* ctxs = (float*)d_out;                  // 18,874,368 B
  float* zs   = (float*)((char*)d_out + 18874368);  // 196,608 B
  us16*  Mt   = (us16*)((char*)d_out + 19070976);   // 16*384*384*2 = 4,718,592 B

  k_wcvt<<<576, 256, 0, stream>>>(wqkv, wout, wbf);
  k_prenorm<<<1024, 256, 0, stream>>>(x, pg, xn);
  k_gemm<<<2304, 512, 0, stream>>>(xn, wbf, qkv, 9, 0);
  k_ctx<<<dim3(64, NS_), 256, 0, stream>>>(qkv, ctxs, zs);
  k_ctxred<<<576, 256, 0, stream>>>(ctxs, zs, ctxred, zred);
  k_ctxw<<<128, 256, 0, stream>>>(ctxred, zred, wbf + 442368, Mt);
  k_qsm<<<256, 256, 0, stream>>>(qkv, Qp);
  k_gemm<<<768, 512, 0, stream>>>(Qp, Mt, y, 3, 1);
  k_outnorm<<<256, 256, 0, stream>>>(y, xn, bout, og, out);
}

// Round 6
// 426.098 us; speedup vs baseline: 2.1165x; 2.1165x over previous
//
#include <hip/hip_runtime.h>
#include <cstdint>
#include <cstddef>

// LinearAttention MI355X round 9: round-8 BK=32/72KB-ring k_gemm with the
// launch_bounds spill fixed — (512,4) capped VGPR at 64 and spilled the
// 64-reg accumulator to scratch (FETCH 649MB, WRITE 1.34GB, 452us).
// (512,2) lets the allocator use ~100 VGPR (still 4 waves/SIMD capable);
// LDS (2x72KB <= 160KB) sets co-residency at 2 blocks/CU.
//
// Layouts (P = 65536 global pixels = b*4096+pix, b in 0..15):
//   xn     bf16 [P][384]
//   qkv    bf16: q [4][P][96] ; ekT [4][96][P] (holds exp(k)) ; vT [4][96][P]
//   Qp     bf16 [P][384]  (softmaxed q, head-interleaved)
//   y      bf16 [P][384]  (at qkv base; q/ekT/vT dead by then)
//   ctxs   fp32 [8][64][96][96] + zs fp32 [8][64][96]   -> scratch in d_out
//   Mt     bf16 [16][384][384]                           -> scratch in d_out
//   ctxred fp32 [64][96][96], zred fp32 [64][96]        -> ws
//   wbf    bf16 Wqkv(1152x384) then Wout(384x384)
//
// ws offsets (bytes): xn @0 (50,331,648) | qkv @50,331,648 (150,994,944)
//   Qp @201,326,592 (50,331,648) | ctxred @251,658,240 (2,359,296)
//   zred @254,017,536 (24,576) | wbf @254,042,112 (1,179,648)
// d_out scratch: ctxs @0 (18,874,368) | zs @18,874,368 (196,608)
//   Mt @19,070,976 (4,718,592; ends 23,789,568) -- dead before k_outnorm.

#define P_     65536
#define P96_   6291456
#define ROW_   384
#define NS_    8            // ctx pixel splits per (b,h)
#define CHK_   512          // 4096 / NS_
#define SCALE_ 0.10206207261596577f
#define EPS_   1e-5f

typedef unsigned short us16;
typedef __attribute__((ext_vector_type(8))) unsigned short ushort8;
typedef __attribute__((ext_vector_type(8))) short short8;
typedef __attribute__((ext_vector_type(4))) float f32x4;
typedef __attribute__((ext_vector_type(2))) unsigned int uint2v;

static __device__ __forceinline__ float bfu2f(us16 u) {
  union { float f; unsigned int i; } x; x.i = ((unsigned int)u) << 16; return x.f;
}
static __device__ __forceinline__ us16 f2bfu(float f) {
  union { float f; unsigned int u; } x; x.f = f;
  unsigned int r = x.u + 0x7fffu + ((x.u >> 16) & 1u);
  return (us16)(r >> 16);
}

#define GLDS16(gp, lp) \
  __builtin_amdgcn_global_load_lds((const __attribute__((address_space(1))) void*)(gp), \
                                   (__attribute__((address_space(3))) void*)(lp), 16, 0, 0)

// ---------------- W fp32 -> bf16 ----------------
__global__ __launch_bounds__(256) void k_wcvt(const float* __restrict__ wqkv,
                                              const float* __restrict__ wout,
                                              us16* __restrict__ wbf) {
  int i = (blockIdx.x * 256 + threadIdx.x) * 4;
  const float* s = (i < 442368) ? (wqkv + i) : (wout + (i - 442368));
  wbf[i + 0] = f2bfu(s[0]); wbf[i + 1] = f2bfu(s[1]);
  wbf[i + 2] = f2bfu(s[2]); wbf[i + 3] = f2bfu(s[3]);
}

// ---------------- K1: prenorm ----------------
__global__ __launch_bounds__(256) void k_prenorm(const float* __restrict__ x,
                                                 const float* __restrict__ g,
                                                 us16* __restrict__ xn) {
  __shared__ float gs[384];
  __shared__ float sm[4][64], sq[4][64];
  int t = threadIdx.x;
  for (int c = t; c < 384; c += 256) gs[c] = g[c];
  int qd = t >> 6, pb = t & 63;
  int p = blockIdx.x * 64 + pb;
  int b = p >> 12, pix = p & 4095;
  const float* xb = x + (size_t)b * 1572864 + pix;
  float xv[96];
  float s1 = 0.f, s2 = 0.f;
  #pragma unroll
  for (int i = 0; i < 96; ++i) {
    float v = xb[(size_t)(qd * 96 + i) * 4096];
    xv[i] = v; s1 += v; s2 += v * v;
  }
  sm[qd][pb] = s1; sq[qd][pb] = s2;
  __syncthreads();
  float su = sm[0][pb] + sm[1][pb] + sm[2][pb] + sm[3][pb];
  float ss = sq[0][pb] + sq[1][pb] + sq[2][pb] + sq[3][pb];
  float mean = su * (1.f / 384);
  float var = ss * (1.f / 384) - mean * mean;
  float rs = rsqrtf(var + EPS_);
  us16* ob = xn + (size_t)p * ROW_ + qd * 96;
  #pragma unroll
  for (int c8 = 0; c8 < 12; ++c8) {
    ushort8 u;
    #pragma unroll
    for (int j = 0; j < 8; ++j)
      u[j] = f2bfu((xv[c8 * 8 + j] - mean) * rs * gs[qd * 96 + c8 * 8 + j]);
    *(ushort8*)(ob + c8 * 8) = u;
  }
}

// ---------------- MFMA GEMM: dst[p][o] = sum_c src[p][c] * W[o][c] --------
// BM=256 BN=128 BK=32, 8 waves (4Mx2N), 3-deep LDS ring (72KB -> 2 blk/CU),
// counted vmcnt(3) (T3+T4), XOR-swizzled staging (T2: g ^= (row>>1)&3 for
// 64B rows), setprio (T5), coalesced LDS epilogue.
// mode 0 (QKV): src=xn, W=Wqkv(1152 rows); q/ekT(exp)/vT sections.
// mode 1 (out): src=Qp, W=Mt (PER-BATCH: W + (p0>>12)*147456); dst y [P][384].
__global__ __launch_bounds__(512, 2) void k_gemm(const us16* __restrict__ src,
                                                 const us16* __restrict__ W,
                                                 us16* __restrict__ dst,
                                                 int MT, int mode) {
  // union buffer: ring of 3 slots {A 256x32 (16KB) + B 128x32 (8KB)} = 72KB;
  // epilogue Cs (max 67.6KB) reuses it.
  __shared__ __align__(16) us16 LDS[36864];
  int i = blockIdx.x;
  int xcd = i & 7, idx = i >> 3;
  int ot = idx % MT;
  int pt = (idx / MT) * 8 + xcd;
  int p0 = pt * 256, o0 = ot * 128;
  int tid = threadIdx.x;
  int wv = tid >> 6, l = tid & 63;
  int wr = wv >> 1, wc = wv & 1;       // 4M x 2N wave grid, 64x64 out per wave
  int lm = l & 15, kq = l >> 4;

  bool rm = (mode != 0) || (ot < 3);   // row-major output section?
  bool isk = (mode == 0) && (ot >= 3) && (ot < 6);
  const us16* Wb = (mode != 0) ? (W + (size_t)(p0 >> 12) * 147456) : W;

  // Staging: rows are 64B = 4 x 16B groups; 4 lanes/row, 16 rows/instruction.
  // Swizzle g ^= (row>>1)&3 applied on the GLOBAL source (LDS dest linear).
  int srow = l >> 2;                       // row within 16-row group
  int swz = ((l & 3) ^ ((l >> 3) & 3)) * 8;
  const us16* aB0 = src + (size_t)(p0 + wv * 32 + srow) * ROW_ + swz;
  const us16* aB1 = src + (size_t)(p0 + wv * 32 + 16 + srow) * ROW_ + swz;
  const us16* bB  = Wb  + (size_t)(o0 + wv * 16 + srow) * ROW_ + swz;

  // Fragment ds_read offsets (short8 units): row*4 + (kq ^ ((row>>1)&3)),
  // (row>>1)&3 == (lm>>1)&3 since row-base is a multiple of 16.
  int fswz = (lm >> 1) & 3;
  int aidx[4], bidx[4];
  #pragma unroll
  for (int ii = 0; ii < 4; ++ii)
    aidx[ii] = (wr * 64 + ii * 16 + lm) * 4 + (kq ^ fswz);
  #pragma unroll
  for (int jj = 0; jj < 4; ++jj)
    bidx[jj] = (wc * 64 + jj * 16 + lm) * 4 + (kq ^ fswz);

  f32x4 acc[4][4];
  #pragma unroll
  for (int a = 0; a < 4; ++a)
    #pragma unroll
    for (int q = 0; q < 4; ++q) acc[a][q] = (f32x4)0.f;

  // slot s base (us16): s*12288; B at +8192.
#define STG(t_, s_) do { \
    GLDS16(aB0 + (t_) * 32, &LDS[(s_) * 12288 + (wv * 32) * 32]); \
    GLDS16(aB1 + (t_) * 32, &LDS[(s_) * 12288 + (wv * 32 + 16) * 32]); \
    GLDS16(bB  + (t_) * 32, &LDS[(s_) * 12288 + 8192 + (wv * 16) * 32]); \
  } while (0)

  // Prologue: stage tiles 0 and 1 (6 loads in flight); wait for tile 0 only.
  STG(0, 0);
  STG(1, 1);
  asm volatile("s_waitcnt vmcnt(3)\n\ts_barrier" ::: "memory");

  #pragma unroll
  for (int t = 0; t < 12; ++t) {
    if (t + 2 < 12) STG(t + 2, (t + 2) % 3);
    const short8* A8 = (const short8*)(LDS + (t % 3) * 12288);
    const short8* B8 = (const short8*)(LDS + (t % 3) * 12288 + 8192);
    __builtin_amdgcn_s_setprio(1);
    {
      short8 af[4], bf[4];
      #pragma unroll
      for (int ii = 0; ii < 4; ++ii) af[ii] = A8[aidx[ii]];
      #pragma unroll
      for (int jj = 0; jj < 4; ++jj) bf[jj] = B8[bidx[jj]];
      if (rm) {
        // C^T fragment: D[row=o][col=p]
        #pragma unroll
        for (int ii = 0; ii < 4; ++ii)
          #pragma unroll
          for (int jj = 0; jj < 4; ++jj)
            acc[ii][jj] = __builtin_amdgcn_mfma_f32_16x16x32_bf16(bf[jj], af[ii], acc[ii][jj], 0, 0, 0);
      } else {
        // C fragment: D[row=p][col=o]
        #pragma unroll
        for (int ii = 0; ii < 4; ++ii)
          #pragma unroll
          for (int jj = 0; jj < 4; ++jj)
            acc[ii][jj] = __builtin_amdgcn_mfma_f32_16x16x32_bf16(af[ii], bf[jj], acc[ii][jj], 0, 0, 0);
      }
    }
    __builtin_amdgcn_s_setprio(0);
    // Boundary: counted vmcnt -- loads for t+2 stay in flight across the
    // barrier; lgkmcnt(0) so ds_reads are serviced before slot reuse.
    if (t < 11) {
      if (t + 2 < 12)
        asm volatile("s_waitcnt vmcnt(3) lgkmcnt(0)\n\ts_barrier" ::: "memory");
      else
        asm volatile("s_waitcnt vmcnt(0) lgkmcnt(0)\n\ts_barrier" ::: "memory");
    }
  }
#undef STG

  // ---- epilogue: stage C through LDS, emit coalesced 16B global stores ----
  __syncthreads();
  us16* Cs = LDS;
  const int MS = rm ? 136 : 264;
  #pragma unroll
  for (int ii = 0; ii < 4; ++ii) {
    #pragma unroll
    for (int jj = 0; jj < 4; ++jj) {
      f32x4 v = acc[ii][jj];
      if (isk) {
        #pragma unroll
        for (int r = 0; r < 4; ++r) v[r] = __expf(v[r]);
      }
      alignas(8) us16 b4[4];
      #pragma unroll
      for (int r = 0; r < 4; ++r) b4[r] = f2bfu(v[r]);
      int maj = rm ? (wr * 64 + ii * 16 + lm) : (wc * 64 + jj * 16 + lm);
      int mnr = rm ? (wc * 64 + jj * 16 + kq * 4) : (wr * 64 + ii * 16 + kq * 4);
      *(uint2v*)&Cs[maj * MS + mnr] = *(const uint2v*)b4;
    }
  }
  __syncthreads();

  if (!rm) {
    // ekT/vT: dst[sec*P96 + d*P_ + p], contiguous along p. Coalesced 512B runs.
    #pragma unroll
    for (int it = 0; it < 8; ++it) {
      int c = it * 512 + tid;
      int o_l = c >> 5, p8 = c & 31;
      int o = o0 + o_l, sec = o / 96, d = o - sec * 96;
      ushort8 u = *(const ushort8*)&Cs[o_l * 264 + p8 * 8];
      *(ushort8*)(dst + (size_t)sec * P96_ + (size_t)d * P_ + p0 + p8 * 8) = u;
    }
  } else if (mode) {
    // y[P][384]: 16 threads cover one 256B row chunk-run.
    #pragma unroll
    for (int it = 0; it < 8; ++it) {
      int c = it * 512 + tid;
      int p_l = c >> 4, ch = c & 15;
      ushort8 u = *(const ushort8*)&Cs[p_l * 136 + ch * 8];
      *(ushort8*)(dst + (size_t)(p0 + p_l) * ROW_ + o0 + ch * 8) = u;
    }
  } else {
    // q sections [P][96]: runs of 192B per p-row (16B-aligned chunks).
    #pragma unroll
    for (int it = 0; it < 8; ++it) {
      int c = it * 512 + tid;
      int p_l = c >> 4, ch = c & 15;
      int o = o0 + ch * 8, sec = o / 96, d = o - sec * 96;
      ushort8 u = *(const ushort8*)&Cs[p_l * 136 + ch * 8];
      *(ushort8*)(dst + (size_t)sec * P96_ + (size_t)(p0 + p_l) * 96 + d) = u;
    }
  }
}

// ---------------- K4: MFMA ctx. ctxs[s][bh][d][e] = sum_p ek[d,p] v[e,p] --
__global__ __launch_bounds__(256) void k_ctx(const us16* __restrict__ qkv,
                                             float* __restrict__ ctxs,
                                             float* __restrict__ zs) {
  __shared__ __align__(16) us16 Ek[96 * 64];
  __shared__ __align__(16) us16 Vv[96 * 64];
  int bh = blockIdx.x, s = blockIdx.y;
  int b = bh >> 2, h = bh & 3;
  const us16* kb = qkv + (size_t)(4 + h) * P96_;
  const us16* vb = qkv + (size_t)(8 + h) * P96_;
  int pbase = b * 4096 + s * CHK_;
  int t = threadIdx.x;
  int wv = t >> 6, l = t & 63;
  int wr = wv >> 1, wc = wv & 1;
  int lm = l & 15, kq = l >> 4;

  f32x4 acc[3][3];
  f32x4 accz[3];
  #pragma unroll
  for (int a = 0; a < 3; ++a) {
    accz[a] = (f32x4)0.f;
    #pragma unroll
    for (int q = 0; q < 3; ++q) acc[a][q] = (f32x4)0.f;
  }
  short8 vone;
  #pragma unroll
  for (int j = 0; j < 8; ++j) vone[j] = (short)0x3F80;   // bf16 1.0

  int srow = wv * 24 + (l >> 3);
  int sgrp = l & 7;

  for (int tile = 0; tile < CHK_ / 64; ++tile) {
    int p0 = pbase + tile * 64;
    #pragma unroll
    for (int c = 0; c < 3; ++c) {
      int r = srow + c * 8;
      int g = sgrp ^ (r & 7);
      GLDS16(kb + (size_t)r * P_ + p0 + g * 8, &Ek[(wv * 24 + c * 8) * 64]);
      GLDS16(vb + (size_t)r * P_ + p0 + g * 8, &Vv[(wv * 24 + c * 8) * 64]);
    }
    __syncthreads();
    const short8* A8 = (const short8*)Ek;
    const short8* B8 = (const short8*)Vv;
    #pragma unroll
    for (int ks = 0; ks < 2; ++ks) {
      short8 af[3], bf[3];
      #pragma unroll
      for (int ii = 0; ii < 3; ++ii) {
        int m = wr * 48 + ii * 16 + lm;
        af[ii] = A8[m * 8 + (((ks * 4 + kq) ^ m) & 7) + ((ks * 4 + kq) & 8)];
        int e = wc * 48 + ii * 16 + lm;
        bf[ii] = B8[e * 8 + (((ks * 4 + kq) ^ e) & 7) + ((ks * 4 + kq) & 8)];
      }
      #pragma unroll
      for (int ii = 0; ii < 3; ++ii)
        #pragma unroll
        for (int jj = 0; jj < 3; ++jj)
          acc[ii][jj] = __builtin_amdgcn_mfma_f32_16x16x32_bf16(af[ii], bf[jj], acc[ii][jj], 0, 0, 0);
      if (wc == 0) {
        #pragma unroll
        for (int ii = 0; ii < 3; ++ii)
          accz[ii] = __builtin_amdgcn_mfma_f32_16x16x32_bf16(af[ii], vone, accz[ii], 0, 0, 0);
      }
    }
    __syncthreads();
  }

  float* cb = ctxs + (size_t)(s * 64 + bh) * 9216;
  #pragma unroll
  for (int ii = 0; ii < 3; ++ii) {
    int m0 = wr * 48 + ii * 16 + kq * 4;
    #pragma unroll
    for (int jj = 0; jj < 3; ++jj) {
      int e = wc * 48 + jj * 16 + lm;
      #pragma unroll
      for (int r = 0; r < 4; ++r)
        cb[(size_t)(m0 + r) * 96 + e] = acc[ii][jj][r];
    }
  }
  if (wc == 0 && lm == 0) {
    #pragma unroll
    for (int ii = 0; ii < 3; ++ii) {
      int m0 = wr * 48 + ii * 16 + kq * 4;
      #pragma unroll
      for (int r = 0; r < 4; ++r)
        zs[(size_t)(s * 64 + bh) * 96 + m0 + r] = accz[ii][r];
    }
  }
}

// ---------------- K4b: reduce the NS_ split slices ------------------------
__global__ __launch_bounds__(256) void k_ctxred(const float* __restrict__ ctxs,
                                                const float* __restrict__ zs,
                                                float* __restrict__ ctx,
                                                float* __restrict__ zr) {
  int bh = blockIdx.x / 9, part = blockIdx.x % 9;
  int t = threadIdx.x;
  int idx = part * 1024 + t * 4;
  f32x4 sum = (f32x4)0.f;
  #pragma unroll
  for (int s = 0; s < NS_; ++s)
    sum += *(const f32x4*)&ctxs[(size_t)(s * 64 + bh) * 9216 + idx];
  *(f32x4*)&ctx[(size_t)bh * 9216 + idx] = sum;
  if (part == 0 && t < 96) {
    float z = 0.f;
    #pragma unroll
    for (int s = 0; s < NS_; ++s) z += zs[(size_t)(s * 64 + bh) * 96 + t];
    zr[bh * 96 + t] = z;
  }
}

// ---------------- K4c: Mt[b][o][h*96+d] = zinv[d] * sum_e ctx[bh][d][e]*Wout[o][h*96+e]
// Tiny MFMA GEMM, hi/lo bf16 split of ctx for ~fp32 accuracy.
// grid 128: blockIdx.x = bh*2 + half (bh 0..63); per block: 192 o x 96 d, K=96.
__global__ __launch_bounds__(256) void k_ctxw(const float* __restrict__ ctx,
                                              const float* __restrict__ zr,
                                              const us16* __restrict__ wout,
                                              us16* __restrict__ Mt) {
  __shared__ __align__(16) us16 Aw[192 * 104];   // Wout slice, padded rows
  __shared__ __align__(16) us16 Bh[96 * 104];    // ctx hi
  __shared__ __align__(16) us16 Bl[96 * 104];    // ctx lo
  int bh = blockIdx.x >> 1, half = blockIdx.x & 1;
  int b = bh >> 2, h = bh & 3;
  int o0 = half * 192;
  int t = threadIdx.x;

  // stage A (Wout rows o0..o0+191, cols h*96..+95): reg-staged, padded LDS
  #pragma unroll
  for (int it = 0; it < 9; ++it) {
    int c = it * 256 + t;             // 16B chunk id, 2304 total
    int row = c / 12, e8 = c % 12;
    ushort8 u = *(const ushort8*)(wout + (size_t)(o0 + row) * 384 + h * 96 + e8 * 8);
    *(ushort8*)&Aw[row * 104 + e8 * 8] = u;
  }
  // stage B: ctx fp32 -> bf16 hi/lo
  const float* cb = ctx + (size_t)bh * 9216;
  #pragma unroll
  for (int it = 0; it < 9; ++it) {
    int c = it * 256 + t;             // f32x4 chunk id, 2304 total
    int fi = c * 4;
    int row = fi / 96, e = fi % 96;
    f32x4 v = *(const f32x4*)&cb[fi];
    alignas(8) us16 hi[4], lo[4];
    #pragma unroll
    for (int r = 0; r < 4; ++r) {
      hi[r] = f2bfu(v[r]);
      lo[r] = f2bfu(v[r] - bfu2f(hi[r]));
    }
    *(uint2v*)&Bh[row * 104 + e] = *(const uint2v*)hi;
    *(uint2v*)&Bl[row * 104 + e] = *(const uint2v*)lo;
  }
  __syncthreads();

  int wv = t >> 6, l = t & 63;
  int lm = l & 15, kq = l >> 4;
  f32x4 acc[3][6];
  #pragma unroll
  for (int a = 0; a < 3; ++a)
    #pragma unroll
    for (int q = 0; q < 6; ++q) acc[a][q] = (f32x4)0.f;

  const short8* A8 = (const short8*)Aw;    // row stride 13 chunks
  const short8* B8h = (const short8*)Bh;
  const short8* B8l = (const short8*)Bl;
  #pragma unroll
  for (int ks = 0; ks < 3; ++ks) {
    short8 af[3];
    #pragma unroll
    for (int ii = 0; ii < 3; ++ii)
      af[ii] = A8[(wv * 48 + ii * 16 + lm) * 13 + ks * 4 + kq];
    #pragma unroll
    for (int jj = 0; jj < 6; ++jj) {
      short8 bh8 = B8h[(jj * 16 + lm) * 13 + ks * 4 + kq];
      short8 bl8 = B8l[(jj * 16 + lm) * 13 + ks * 4 + kq];
      #pragma unroll
      for (int ii = 0; ii < 3; ++ii) {
        acc[ii][jj] = __builtin_amdgcn_mfma_f32_16x16x32_bf16(af[ii], bh8, acc[ii][jj], 0, 0, 0);
        acc[ii][jj] = __builtin_amdgcn_mfma_f32_16x16x32_bf16(af[ii], bl8, acc[ii][jj], 0, 0, 0);
      }
    }
  }

  // D[row=o][col=d]: col = jj*16+lm (d), rows kq*4+r within o 16-block.
  us16* mb = Mt + (size_t)b * 147456;
  #pragma unroll
  for (int jj = 0; jj < 6; ++jj) {
    int d = jj * 16 + lm;
    float zinv = 1.0f / zr[bh * 96 + d];
    #pragma unroll
    for (int ii = 0; ii < 3; ++ii) {
      int orow = o0 + wv * 48 + ii * 16 + kq * 4;
      #pragma unroll
      for (int r = 0; r < 4; ++r)
        mb[(size_t)(orow + r) * 384 + h * 96 + d] = f2bfu(acc[ii][jj][r] * zinv);
    }
  }
}

// ---------------- K5: Q'[p][h*96+d] = softmax_d(q_h[p])*SCALE, bf16 -------
__global__ __launch_bounds__(256) void k_qsm(const us16* __restrict__ qkv,
                                             us16* __restrict__ Qp) {
  int p = blockIdx.x * 256 + threadIdx.x;
  #pragma unroll 1
  for (int h = 0; h < 4; ++h) {
    const us16* qrow = qkv + (size_t)h * P96_ + (size_t)p * 96;
    float qv[96];
    #pragma unroll
    for (int c8 = 0; c8 < 12; ++c8) {
      ushort8 u = *(const ushort8*)(qrow + c8 * 8);
      #pragma unroll
      for (int j = 0; j < 8; ++j) qv[c8 * 8 + j] = bfu2f(u[j]);
    }
    float m = -1e30f;
    #pragma unroll
    for (int d = 0; d < 96; ++d) m = fmaxf(m, qv[d]);
    float s = 0.f;
    #pragma unroll
    for (int d = 0; d < 96; ++d) { qv[d] = __expf(qv[d] - m); s += qv[d]; }
    float sc = SCALE_ / s;
    us16* ob = Qp + (size_t)p * ROW_ + h * 96;
    #pragma unroll
    for (int c8 = 0; c8 < 12; ++c8) {
      ushort8 u;
      #pragma unroll
      for (int j = 0; j < 8; ++j) u[j] = f2bfu(qv[c8 * 8 + j] * sc);
      *(ushort8*)(ob + c8 * 8) = u;
    }
  }
}

// ---------------- K7: +bias, channel LN, *g, +xn, write channel-major fp32
__global__ __launch_bounds__(256) void k_outnorm(const us16* __restrict__ y,
                                                 const us16* __restrict__ xn,
                                                 const float* __restrict__ bout,
                                                 const float* __restrict__ g,
                                                 float* __restrict__ out) {
  __shared__ float bs[384], gs[384];
  int t = threadIdx.x;
  for (int c = t; c < 384; c += 256) { bs[c] = bout[c]; gs[c] = g[c]; }
  __syncthreads();
  int p = blockIdx.x * 256 + t;
  int b = p >> 12, pix = p & 4095;
  const us16* yb = y + (size_t)p * ROW_;
  const us16* xb = xn + (size_t)p * ROW_;
  float sum = 0.f, sq = 0.f;
  #pragma unroll 4
  for (int c8 = 0; c8 < 48; ++c8) {
    ushort8 u = *(const ushort8*)(yb + c8 * 8);
    #pragma unroll
    for (int j = 0; j < 8; ++j) {
      float v = bfu2f(u[j]) + bs[c8 * 8 + j];
      sum += v; sq += v * v;
    }
  }
  float mean = sum * (1.f / 384);
  float var = sq * (1.f / 384) - mean * mean;
  float rs = rsqrtf(var + EPS_);
  float* oB = out + (size_t)b * 1572864 + pix;
  #pragma unroll 2
  for (int c8 = 0; c8 < 48; ++c8) {
    ushort8 u = *(const ushort8*)(yb + c8 * 8);
    ushort8 ux = *(const ushort8*)(xb + c8 * 8);
    #pragma unroll
    for (int j = 0; j < 8; ++j) {
      int c = c8 * 8 + j;
      float v = bfu2f(u[j]) + bs[c];
      oB[(size_t)c * 4096] = (v - mean) * rs * gs[c] + bfu2f(ux[j]);
    }
  }
}

extern "C" void kernel_launch(void* const* d_in, const int* in_sizes, int n_in,
                              void* d_out, int out_size, void* d_ws, size_t ws_size,
                              hipStream_t stream) {
  const float* x    = (const float*)d_in[0];
  const float* pg   = (const float*)d_in[1];
  const float* wqkv = (const float*)d_in[2];
  const float* wout = (const float*)d_in[3];
  const float* bout = (const float*)d_in[4];
  const float* og   = (const float*)d_in[5];

  char* ws = (char*)d_ws;
  us16*  xn     = (us16*)(ws);
  us16*  qkv    = (us16*)(ws + 50331648);
  us16*  Qp     = (us16*)(ws + 201326592);      // softmaxed q
  float* ctxred = (float*)(ws + 251658240);
  float* zred   = (float*)(ws + 254017536);
  us16*  wbf    = (us16*)(ws + 254042112);
  us16*  y      = qkv;                          // q/ekT/vT dead after qsm/gemm1
  float* out    = (float*)d_out;
  // d_out as pre-epilogue scratch (dead until k_outnorm):
  float* ctxs = (float*)d_out;                  // 18,874,368 B
  float* zs   = (float*)((char*)d_out + 18874368);  // 196,608 B
  us16*  Mt   = (us16*)((char*)d_out + 19070976);   // 16*384*384*2 = 4,718,592 B

  k_wcvt<<<576, 256, 0, stream>>>(wqkv, wout, wbf);
  k_prenorm<<<1024, 256, 0, stream>>>(x, pg, xn);
  k_gemm<<<2304, 512, 0, stream>>>(xn, wbf, qkv, 9, 0);
  k_ctx<<<dim3(64, NS_), 256, 0, stream>>>(qkv, ctxs, zs);
  k_ctxred<<<576, 256, 0, stream>>>(ctxs, zs, ctxred, zred);
  k_ctxw<<<128, 256, 0, stream>>>(ctxred, zred, wbf + 442368, Mt);
  k_qsm<<<256, 256, 0, stream>>>(qkv, Qp);
  k_gemm<<<768, 512, 0, stream>>>(Qp, Mt, y, 3, 1);
  k_outnorm<<<256, 256, 0, stream>>>(y, xn, bout, og, out);
}